// Round 9
// baseline (213.146 us; speedup 1.0000x reference)
//
#include <hip/hip_runtime.h>

// ---------------- literal building blocks (transliteration of the numpy ref) ----------------

// H-gate entry: kron over 4 factors, qubit 0 = MSB (first kron factor), H = [[1,1],[1,-1]]/sqrt2
__device__ inline float hprod(int hq, int r, int c) {
    float v = 1.0f;
    for (int q = 0; q < 4; ++q) {
        int br = (r >> (3 - q)) & 1, bc = (c >> (3 - q)) & 1;
        if (q == hq) v *= 0.70710678118654752f * ((br & bc) ? -1.0f : 1.0f);
        else if (br != bc) return 0.0f;   // I2 factor
    }
    return v;
}

// _blk(e, c0, c3)[i][j]: [[c0,0,0,0],[0,a,b,0],[0,b,a,0],[0,0,0,c3]], a=(e+1)/2, b=(e-1)/2
__device__ inline float2 blk_e(float2 e, float2 c0, float2 c3, int i, int j) {
    float2 z = make_float2(0.f, 0.f);
    float2 a = make_float2((e.x + 1.f) * .5f, e.y * .5f);
    float2 b = make_float2((e.x - 1.f) * .5f, e.y * .5f);
    if (i == 0) return (j == 0) ? c0 : z;
    if (i == 3) return (j == 3) ? c3 : z;
    if (i == 1) return (j == 1) ? a : (j == 2 ? b : z);
    /* i==2 */  return (j == 2) ? a : (j == 1 ? b : z);
}

// _U16(t)[r][c] = kron(P00,U00) + kron(P11,U11) + kron(Ppp,Up) + kron(Pmm,I4)
// kron(A,B)[r][c] = A[r>>2][c>>2] * B[r&3][c&3];  P = outer(v, v) for real v
__device__ inline float2 u16_lit(int r, int c, float2 ep) {
    const float rt = 0.70710678118654752f;
    const float s00[4] = {1.f, 0.f, 0.f, 0.f};
    const float s11[4] = {0.f, 0.f, 0.f, 1.f};
    const float sp[4]  = {0.f,  rt,  rt, 0.f};
    const float sm[4]  = {0.f,  rt, -rt, 0.f};
    float2 em  = make_float2(ep.x, -ep.y);
    float2 one = make_float2(1.f, 0.f);
    int pr = r >> 2, qr = r & 3, pc = c >> 2, qc = c & 3;
    float2 acc = make_float2(0.f, 0.f);
    float p;
    p = s00[pr] * s00[pc];
    if (p != 0.f) { float2 u = blk_e(em, one, em, qr, qc); acc.x += p * u.x; acc.y += p * u.y; }
    p = s11[pr] * s11[pc];
    if (p != 0.f) { float2 u = blk_e(ep, ep, one, qr, qc); acc.x += p * u.x; acc.y += p * u.y; }
    p = sp[pr] * sp[pc];
    if (p != 0.f && qr == qc) {              // Up = diag(ep, 1, 1, em)
        float2 u = (qr == 0) ? ep : (qr == 3 ? em : one);
        acc.x += p * u.x; acc.y += p * u.y;
    }
    p = sm[pr] * sm[pc];
    if (p != 0.f && qr == qc) acc.x += p;    // I4
    return acc;
}

// _swap row map: sw = r with bits at shift positions pi,pj exchanged
__device__ inline int swrow(int r, int pi, int pj) {
    int bi = (r >> pi) & 1, bj = (r >> pj) & 1, d = bi ^ bj;
    return r ^ ((d << pi) | (d << pj));
}

// ---------------- gate precompute: 1 block, 256 threads, literal chain ----------------
__global__ void qft_gate_kernel(const float* __restrict__ thetas, float2* __restrict__ gate) {
    __shared__ float2 A[2][16][16];
    int t = threadIdx.x, i = t >> 4, j = t & 15;
    int cur = 0;
    A[0][i][j] = make_float2((i == j) ? 1.f : 0.f, 0.f);   // oper = eye(16)
    __syncthreads();
    // literal loop: for qi in 0..3: oper = H_qi @ oper; then (3-qi) x oper = U16(theta_n) @ oper
    const signed char kind [10] = {-1, 0, 0, 0, -1, 0, 0, -1, 0, -1};  // -1 = H, 0 = U16
    const signed char param[10] = { 0, 0, 1, 2,  1, 3, 4,  2, 5,  3};  // H qubit / theta index
    for (int s = 0; s < 10; ++s) {
        float2 acc = make_float2(0.f, 0.f);
        if (kind[s] < 0) {
            int hq = param[s];
            for (int k = 0; k < 16; ++k) {
                float g = hprod(hq, i, k);
                acc.x = fmaf(g, A[cur][k][j].x, acc.x);
                acc.y = fmaf(g, A[cur][k][j].y, acc.y);
            }
        } else {
            float th = thetas[(int)param[s]];
            // HYPOTHESIS UNDER TEST (C1): effective exponent is e^{-it} where my
            // translation had e^{+it} — statistical fingerprint of R2/R3/R6 absmax
            // (var 1.98 / 2.14 / 1.34) uniquely selects a GLOBAL CONJUGATION of the gate:
            // R2's var is parameter-free 2.0 under this hypothesis, measured 1.98.
            float2 ep = make_float2(cosf(th), -sinf(th));
            for (int k = 0; k < 16; ++k) {
                float2 u = u16_lit(i, k, ep);
                float2 x = A[cur][k][j];
                acc.x += u.x * x.x - u.y * x.y;
                acc.y += u.x * x.y + u.y * x.x;
            }
        }
        A[cur ^ 1][i][j] = acc;
        cur ^= 1;
        __syncthreads();
    }
    // oper = _SW03 @ oper : row gather with _swap(0,3) -> bit positions (3,0)
    A[cur ^ 1][i][j] = A[cur][swrow(i, 3, 0)][j];
    cur ^= 1; __syncthreads();
    // oper = _SW12 @ oper : _swap(1,2) -> bit positions (2,1)
    A[cur ^ 1][i][j] = A[cur][swrow(i, 2, 1)][j];
    cur ^= 1; __syncthreads();
    gate[i * 16 + j] = A[cur][i][j];
}

// ---------------- bf16 pack (RNE) ----------------
__device__ inline unsigned int f2bf(float f) {
    unsigned int u = __float_as_uint(f);
    u += 0x7fffu + ((u >> 16) & 1u);
    return u >> 16;
}

// ---------------- main apply: out[b,i,m] = sum_j gate[i,j] * (re + i*im)[b,j,m] ----------------
// One 64-lane wave per batch; each lane owns m = 2*lane, 2*lane+1.
// OUTPUT: INTERLEAVED bf16 — [B][16][M][re,im] (complex64.view(float32) order).
__global__ __launch_bounds__(256) void qft_apply_kernel(
    const float* __restrict__ re, const float* __restrict__ im,
    const float2* __restrict__ gate, unsigned short* __restrict__ out)
{
    int b = blockIdx.x * 4 + (threadIdx.x >> 6);
    int lane = threadIdx.x & 63;

    const float2* pr = reinterpret_cast<const float2*>(re + b * 2048) + lane;
    const float2* pi = reinterpret_cast<const float2*>(im + b * 2048) + lane;

    float2 xr[16], xi[16];
#pragma unroll
    for (int j = 0; j < 16; ++j) {
        xr[j] = pr[j * 64];
        xi[j] = pi[j * 64];
    }

    unsigned short* po = out + (size_t)b * 4096 + lane * 4;
#pragma unroll
    for (int i = 0; i < 16; ++i) {
        float ar0 = 0.f, ai0 = 0.f, ar1 = 0.f, ai1 = 0.f;
#pragma unroll
        for (int j = 0; j < 16; ++j) {
            float2 g = gate[i * 16 + j];  // wave-uniform
            ar0 = fmaf(g.x, xr[j].x, ar0); ar0 = fmaf(-g.y, xi[j].x, ar0);
            ai0 = fmaf(g.y, xr[j].x, ai0); ai0 = fmaf(g.x, xi[j].x, ai0);
            ar1 = fmaf(g.x, xr[j].y, ar1); ar1 = fmaf(-g.y, xi[j].y, ar1);
            ai1 = fmaf(g.y, xr[j].y, ai1); ai1 = fmaf(g.x, xi[j].y, ai1);
        }
        uint2 w;
        w.x = f2bf(ar0) | (f2bf(ai0) << 16);
        w.y = f2bf(ar1) | (f2bf(ai1) << 16);
        *reinterpret_cast<uint2*>(po + (size_t)i * 256) = w;
    }
}

extern "C" void kernel_launch(void* const* d_in, const int* in_sizes, int n_in,
                              void* d_out, int out_size, void* d_ws, size_t ws_size,
                              hipStream_t stream) {
    // Wiring per R6 evidence: d_in[0] = "inputs_im", d_in[1] = "inputs_re" (sorted keys),
    // d_in[2] = "thetas"; output interleaved complex-view bf16.
    const float* im = (const float*)d_in[0];
    const float* re = (const float*)d_in[1];
    const float* th = (const float*)d_in[2];
    float2* gate = (float2*)d_ws;              // 2 KiB scratch
    unsigned short* out = (unsigned short*)d_out;

    qft_gate_kernel<<<1, 256, 0, stream>>>(th, gate);

    int B = in_sizes[0] / (16 * 128);          // 8192
    qft_apply_kernel<<<B / 4, 256, 0, stream>>>(re, im, gate, out);
}

// Round 10
// 181.922 us; speedup vs baseline: 1.1716x; 1.1716x over previous
//
#include <hip/hip_runtime.h>

// ---------------- bf16 pack (RNE) ----------------
__device__ inline unsigned int f2bf(float f) {
    unsigned int u = __float_as_uint(f);
    u += 0x7fffu + ((u >> 16) & 1u);
    return u >> 16;
}

// Sparse row of U16(theta): every row has <= 2 nonzeros.
// U16 = kron(P00,U00) + kron(P11,U11) + kron(Ppp,Up) + kron(Pmm,I4), row r = 4*pr + qr.
//   pr==0: U00 = blk(em, 1, em) rows; pr==3: U11 = blk(ep, ep, 1) rows (cols offset 12)
//   pr in {1,2}: entries at cols 4+qr and 8+qr: 0.5*Up[qr] +/- 0.5  (Up = diag(ep,1,1,em))
// a(e) = (e+1)/2, b(e) = (e-1)/2. ep passed in is ALREADY the effective exponent.
__device__ inline void u16_row(int r, float2 ep, int* c0, float2* v0, int* c1, float2* v1) {
    float2 em   = make_float2(ep.x, -ep.y);
    float2 one  = make_float2(1.f, 0.f);
    float2 zero = make_float2(0.f, 0.f);
    int pr = r >> 2, qr = r & 3;
    if (pr == 0 || pr == 3) {
        float2 e   = (pr == 0) ? em  : ep;   // U00 built from em, U11 from ep
        float2 cc0 = (pr == 0) ? one : ep;   // corner [0][0]
        float2 cc3 = (pr == 0) ? em  : one;  // corner [3][3]
        int base = (pr == 0) ? 0 : 12;
        float2 a = make_float2((e.x + 1.f) * .5f, e.y * .5f);
        float2 b = make_float2((e.x - 1.f) * .5f, e.y * .5f);
        if      (qr == 0) { *c0 = base + 0; *v0 = cc0; *c1 = base + 0; *v1 = zero; }
        else if (qr == 3) { *c0 = base + 3; *v0 = cc3; *c1 = base + 3; *v1 = zero; }
        else if (qr == 1) { *c0 = base + 1; *v0 = a;   *c1 = base + 2; *v1 = b;    }
        else              { *c0 = base + 1; *v0 = b;   *c1 = base + 2; *v1 = a;    }
    } else {
        float2 up = (qr == 0) ? ep : (qr == 3 ? em : one);
        float hx = up.x * .5f, hy = up.y * .5f;
        float s1 = (pr == 1) ? 0.5f : -0.5f;   // Pmm contribution at pc=1
        float s2 = (pr == 2) ? 0.5f : -0.5f;   // Pmm contribution at pc=2
        *c0 = 4 + qr; *v0 = make_float2(hx + s1, hy);
        *c1 = 8 + qr; *v1 = make_float2(hx + s2, hy);
    }
}

// ---------------- fused kernel: build gate in LDS (per block), then apply ----------------
// One 64-lane wave per batch (4 batches / 256-thread block); lane owns cols m = 2*lane, 2*lane+1.
// Wiring (R9-verified): d_in[0]=inputs_im, d_in[1]=inputs_re (sorted npz keys), conj exponent.
// Output: interleaved bf16 [B][16][M][re,im].
__global__ __launch_bounds__(256, 4) void qft_fused_kernel(
    const float* __restrict__ re, const float* __restrict__ im,
    const float* __restrict__ thetas, unsigned short* __restrict__ out)
{
    __shared__ float2 A[2][16][16];   // 4 KiB ping-pong gate chain
    int tid  = threadIdx.x;
    int b    = blockIdx.x * 4 + (tid >> 6);
    int lane = tid & 63;
    int gi = tid >> 4, gj = tid & 15;

    // ---- issue the 32 input loads first (held in VGPRs across the gate build) ----
    const float2* pr = reinterpret_cast<const float2*>(re + b * 2048) + lane;
    const float2* pi = reinterpret_cast<const float2*>(im + b * 2048) + lane;
    float2 xr[16], xi[16];
#pragma unroll
    for (int j = 0; j < 16; ++j) { xr[j] = pr[j * 64]; xi[j] = pi[j * 64]; }

    // ---- build the 16x16 gate in LDS: 10 sparse steps, <=2 nonzeros/row each ----
    A[0][gi][gj] = make_float2((gi == gj) ? 1.f : 0.f, 0.f);   // oper = eye(16)
    __syncthreads();
    const signed char kind [10] = {-1, 0, 0, 0, -1, 0, 0, -1, 0, -1};  // -1=H, 0=U16
    const signed char param[10] = { 0, 0, 1, 2,  1, 3, 4,  2, 5,  3};  // H qubit / theta idx
#pragma unroll
    for (int s = 0; s < 10; ++s) {
        int src = s & 1, dst = src ^ 1;
        float2 acc;
        if (kind[s] < 0) {
            // H on qubit hq (bit p = 3-hq): (H A)[i] = rt*A[i0] + (bit? -rt : rt)*A[i1]
            int p  = 3 - param[s];
            int i0 = gi & ~(1 << p), i1 = gi | (1 << p);
            const float rt = 0.70710678118654752f;
            float sg = ((gi >> p) & 1) ? -rt : rt;
            float2 a0 = A[src][i0][gj], a1 = A[src][i1][gj];
            acc.x = rt * a0.x + sg * a1.x;
            acc.y = rt * a0.y + sg * a1.y;
        } else {
            float th = thetas[(int)param[s]];
            float2 ep = make_float2(cosf(th), -sinf(th));   // conjugated exponent (R9-verified)
            int c0, c1; float2 v0, v1;
            u16_row(gi, ep, &c0, &v0, &c1, &v1);
            float2 a0 = A[src][c0][gj], a1 = A[src][c1][gj];
            acc.x = v0.x * a0.x - v0.y * a0.y + v1.x * a1.x - v1.y * a1.y;
            acc.y = v0.x * a0.y + v0.y * a0.x + v1.x * a1.y + v1.y * a1.x;
        }
        A[dst][gi][gj] = acc;
        __syncthreads();
    }
    // After 10 steps result sits in A[0]. SW12@SW03 = 4-bit reversal, folded into row index.

    // ---- apply: out[b,i,m] = sum_j gate[i,j] * x[j,m], gate row i = A[0][rev4(i)] ----
    unsigned short* po = out + (size_t)b * 4096 + lane * 4;
#pragma unroll
    for (int i = 0; i < 16; ++i) {
        const int rr = ((i & 1) << 3) | ((i & 2) << 1) | ((i & 4) >> 1) | ((i & 8) >> 3);
        float ar0 = 0.f, ai0 = 0.f, ar1 = 0.f, ai1 = 0.f;
#pragma unroll
        for (int j = 0; j < 16; ++j) {
            float2 g = A[0][rr][j];   // wave-uniform LDS read -> broadcast, conflict-free
            ar0 = fmaf(g.x, xr[j].x, ar0); ar0 = fmaf(-g.y, xi[j].x, ar0);
            ai0 = fmaf(g.y, xr[j].x, ai0); ai0 = fmaf(g.x, xi[j].x, ai0);
            ar1 = fmaf(g.x, xr[j].y, ar1); ar1 = fmaf(-g.y, xi[j].y, ar1);
            ai1 = fmaf(g.y, xr[j].y, ai1); ai1 = fmaf(g.x, xi[j].y, ai1);
        }
        uint2 w;
        w.x = f2bf(ar0) | (f2bf(ai0) << 16);
        w.y = f2bf(ar1) | (f2bf(ai1) << 16);
        *reinterpret_cast<uint2*>(po + (size_t)i * 256) = w;
    }
}

extern "C" void kernel_launch(void* const* d_in, const int* in_sizes, int n_in,
                              void* d_out, int out_size, void* d_ws, size_t ws_size,
                              hipStream_t stream) {
    // R9-verified wiring: d_in[0]="inputs_im", d_in[1]="inputs_re" (sorted keys), d_in[2]="thetas"
    const float* im = (const float*)d_in[0];
    const float* re = (const float*)d_in[1];
    const float* th = (const float*)d_in[2];
    unsigned short* out = (unsigned short*)d_out;

    int B = in_sizes[0] / (16 * 128);   // 8192
    qft_fused_kernel<<<B / 4, 256, 0, stream>>>(re, im, th, out);
}

// Round 12
// 179.655 us; speedup vs baseline: 1.1864x; 1.0126x over previous
//
#include <hip/hip_runtime.h>

// ---------------- bf16 pack (RNE) ----------------
__device__ inline unsigned int f2bf(float f) {
    unsigned int u = __float_as_uint(f);
    u += 0x7fffu + ((u >> 16) & 1u);
    return u >> 16;
}

// Sparse row of U16(theta): every row has <= 2 nonzeros (R10-verified PASS).
__device__ inline void u16_row(int r, float2 ep, int* c0, float2* v0, int* c1, float2* v1) {
    float2 em   = make_float2(ep.x, -ep.y);
    float2 one  = make_float2(1.f, 0.f);
    float2 zero = make_float2(0.f, 0.f);
    int pr = r >> 2, qr = r & 3;
    if (pr == 0 || pr == 3) {
        float2 e   = (pr == 0) ? em  : ep;   // U00 from em, U11 from ep
        float2 cc0 = (pr == 0) ? one : ep;
        float2 cc3 = (pr == 0) ? em  : one;
        int base = (pr == 0) ? 0 : 12;
        float2 a = make_float2((e.x + 1.f) * .5f, e.y * .5f);
        float2 b = make_float2((e.x - 1.f) * .5f, e.y * .5f);
        if      (qr == 0) { *c0 = base + 0; *v0 = cc0; *c1 = base + 0; *v1 = zero; }
        else if (qr == 3) { *c0 = base + 3; *v0 = cc3; *c1 = base + 3; *v1 = zero; }
        else if (qr == 1) { *c0 = base + 1; *v0 = a;   *c1 = base + 2; *v1 = b;    }
        else              { *c0 = base + 1; *v0 = b;   *c1 = base + 2; *v1 = a;    }
    } else {
        float2 up = (qr == 0) ? ep : (qr == 3 ? em : one);
        float hx = up.x * .5f, hy = up.y * .5f;
        float s1 = (pr == 1) ? 0.5f : -0.5f;
        float s2 = (pr == 2) ? 0.5f : -0.5f;
        *c0 = 4 + qr; *v0 = make_float2(hx + s1, hy);
        *c1 = 8 + qr; *v1 = make_float2(hx + s2, hy);
    }
}

// ---------------- fused kernel ----------------
// Gate build (10 sparse steps in LDS, per block) then GEMV apply.
// Apply mapping: 1 lane per output column; 128 lanes (2 waves) per batch; 2 batches / 256-block.
// Per-lane state = 16x2 f32 ACCUMULATORS (register-resident by construction).
// Wiring (R9-verified): d_in[0]=inputs_im, d_in[1]=inputs_re, conj exponent e^{-it}.
// Output: interleaved bf16 [B][16][M][re,im].
__global__ __launch_bounds__(256, 4) void qft_fused_kernel(
    const float* __restrict__ re, const float* __restrict__ im,
    const float* __restrict__ thetas, unsigned short* __restrict__ out)
{
    __shared__ float2 A[2][16][16];   // 4 KiB ping-pong; A[1] doubles as transposed gate
    int tid = threadIdx.x;
    int gi = tid >> 4, gj = tid & 15;

    // ---- build the 16x16 gate in LDS: 10 sparse steps, <=2 nonzeros/row each ----
    A[0][gi][gj] = make_float2((gi == gj) ? 1.f : 0.f, 0.f);   // oper = eye(16)
    __syncthreads();
    const signed char kind [10] = {-1, 0, 0, 0, -1, 0, 0, -1, 0, -1};  // -1=H, 0=U16
    const signed char param[10] = { 0, 0, 1, 2,  1, 3, 4,  2, 5,  3};  // H qubit / theta idx
#pragma unroll
    for (int s = 0; s < 10; ++s) {
        int src = s & 1, dst = src ^ 1;
        float2 acc;
        if (kind[s] < 0) {
            int p  = 3 - param[s];
            int i0 = gi & ~(1 << p), i1 = gi | (1 << p);
            const float rt = 0.70710678118654752f;
            float sg = ((gi >> p) & 1) ? -rt : rt;
            float2 a0 = A[src][i0][gj], a1 = A[src][i1][gj];
            acc.x = rt * a0.x + sg * a1.x;
            acc.y = rt * a0.y + sg * a1.y;
        } else {
            float th = thetas[(int)param[s]];
            float2 ep = make_float2(cosf(th), -sinf(th));   // conjugated exponent (R9-verified)
            int c0, c1; float2 v0, v1;
            u16_row(gi, ep, &c0, &v0, &c1, &v1);
            float2 a0 = A[src][c0][gj], a1 = A[src][c1][gj];
            acc.x = v0.x * a0.x - v0.y * a0.y + v1.x * a1.x - v1.y * a1.y;
            acc.y = v0.x * a0.y + v0.y * a0.x + v1.x * a1.y + v1.y * a1.x;
        }
        A[dst][gi][gj] = acc;
        __syncthreads();
    }
    // Final gate sits in A[0]. Write transposed+bit-reversed copy into A[1]:
    //   Gt[j][i] = G[rev4(i)][j]  (folds SW12@SW03 row permutation into the layout)
    {
        int rg = ((gj & 1) << 3) | ((gj & 2) << 1) | ((gj & 4) >> 1) | ((gj & 8) >> 3);
        float2 v = A[0][rg][gi];
        __syncthreads();
        A[1][gi][gj] = v;             // A[1][j][i] layout
        __syncthreads();
    }

    // ---- GEMV apply: acc[i] += Gt[j][i] * x[j], one column per lane ----
    int b   = blockIdx.x * 2 + (tid >> 7);
    int col = tid & 127;
    const float* prr = re + b * 2048 + col;   // [b][j][col], stride 128 floats over j
    const float* pri = im + b * 2048 + col;

    float ar[16], ai[16];
#pragma unroll
    for (int i = 0; i < 16; ++i) { ar[i] = 0.f; ai[i] = 0.f; }

#pragma unroll
    for (int j = 0; j < 16; ++j) {
        float xr = prr[j * 128];
        float xi = pri[j * 128];
#pragma unroll
        for (int i = 0; i < 16; ++i) {
            float2 g = A[1][j][i];    // wave-uniform contiguous LDS row -> broadcast reads
            ar[i] = fmaf(g.x, xr, ar[i]); ar[i] = fmaf(-g.y, xi, ar[i]);
            ai[i] = fmaf(g.y, xr, ai[i]); ai[i] = fmaf(g.x, xi, ai[i]);
        }
    }

    unsigned short* po = out + (size_t)b * 4096 + col * 2;   // [b][i][m][re,im]
#pragma unroll
    for (int i = 0; i < 16; ++i) {
        *reinterpret_cast<unsigned int*>(po + (size_t)i * 256) = f2bf(ar[i]) | (f2bf(ai[i]) << 16);
    }
}

extern "C" void kernel_launch(void* const* d_in, const int* in_sizes, int n_in,
                              void* d_out, int out_size, void* d_ws, size_t ws_size,
                              hipStream_t stream) {
    // R9-verified wiring: d_in[0]="inputs_im", d_in[1]="inputs_re" (sorted keys), d_in[2]="thetas"
    const float* im = (const float*)d_in[0];
    const float* re = (const float*)d_in[1];
    const float* th = (const float*)d_in[2];
    unsigned short* out = (unsigned short*)d_out;

    int B = in_sizes[0] / (16 * 128);   // 8192
    qft_fused_kernel<<<B / 2, 256, 0, stream>>>(re, im, th, out);
}